// Round 6
// baseline (994.803 us; speedup 1.0000x reference)
//
#include <hip/hip_runtime.h>
#include <hip/hip_fp16.h>
#include <math.h>

// PCDONN: 144 fields (M=9 x B=16) of 512x512 complex through 4 angular-spectrum
// propagations (same z -> same H; last two fused as H^2), 3 masks, intensity
// mean over modes, detector readout.
//
// R3: atomic-free k_final (+k_reduce); fp16 field (151 MB).
// R4: hot-path sincos -> hardware v_sin/v_cos (revolutions); k_init keeps libm.
// R5->R6: k_col tile 16->8 columns (64->32 KB LDS): LDS cap was 8 waves/CU
// (binding); now VGPR cap binds at 16 waves/CU. H prefetched into regs so its
// scattered loads overlap the forward FFT.
//
// FFT: per-wave Stockham radix-8 (64 lanes x 8 complex regs, 3 stages),
// XOR-swizzled LDS (sig(j)=j^(j>>3)), no barriers inside (single-wave in-order).

constexpr int HW   = 512 * 512;
constexpr int NF   = 144;  // M*B
constexpr int NB   = 16;
constexpr int NM   = 9;
constexpr int NC   = 10;

__device__ __forceinline__ float2 cmul(float2 a, float2 b) {
    return make_float2(a.x * b.x - a.y * b.y, a.x * b.y + a.y * b.x);
}
__device__ __forceinline__ float2 cadd(float2 a, float2 b) { return make_float2(a.x + b.x, a.y + b.y); }
__device__ __forceinline__ float2 csub(float2 a, float2 b) { return make_float2(a.x - b.x, a.y - b.y); }

template <int S>
__device__ __forceinline__ float2 mulJ(float2 z) {
    return (S < 0) ? make_float2(z.y, -z.x) : make_float2(-z.y, z.x);
}

template <int S>
__device__ __forceinline__ float2 twmul(float2 a, float2 t) {
    float ty = (S < 0) ? t.y : -t.y;
    return make_float2(a.x * t.x - a.y * ty, a.x * ty + a.y * t.x);
}

// fast sincos via v_sin_f32/v_cos_f32 (input in REVOLUTIONS per gfx950 ISA).
__device__ __forceinline__ void fsincos_rev(float rev, float* s, float* c) {
    float r = rev - rintf(rev);       // [-0.5, 0.5]
    *s = __builtin_amdgcn_sinf(r);
    *c = __builtin_amdgcn_cosf(r);
}
// radian-domain version (|x| small, here <= ~25 rad -> reduction err ~1e-6 rad)
__device__ __forceinline__ void fsincos(float x, float* s, float* c) {
    fsincos_rev(x * 0.15915494309189535f, s, c);
}

template <int S>
__device__ __forceinline__ void dft8(const float2 a[8], float2 X[8]) {
    float2 e[4], o[4];
    {
        float2 t0 = cadd(a[0], a[4]), t1 = csub(a[0], a[4]);
        float2 u0 = cadd(a[2], a[6]), u1 = mulJ<S>(csub(a[2], a[6]));
        e[0] = cadd(t0, u0); e[1] = cadd(t1, u1); e[2] = csub(t0, u0); e[3] = csub(t1, u1);
    }
    {
        float2 t0 = cadd(a[1], a[5]), t1 = csub(a[1], a[5]);
        float2 u0 = cadd(a[3], a[7]), u1 = mulJ<S>(csub(a[3], a[7]));
        o[0] = cadd(t0, u0); o[1] = cadd(t1, u1); o[2] = csub(t0, u0); o[3] = csub(t1, u1);
    }
    const float C = 0.70710678118654752f;
    float2 w1 = make_float2(C, (S < 0) ? -C : C);
    float2 w3 = make_float2(-C, (S < 0) ? -C : C);
    o[1] = cmul(o[1], w1);
    o[2] = mulJ<S>(o[2]);
    o[3] = cmul(o[3], w3);
    X[0] = cadd(e[0], o[0]); X[4] = csub(e[0], o[0]);
    X[1] = cadd(e[1], o[1]); X[5] = csub(e[1], o[1]);
    X[2] = cadd(e[2], o[2]); X[6] = csub(e[2], o[2]);
    X[3] = cadd(e[3], o[3]); X[7] = csub(e[3], o[3]);
}

__device__ __forceinline__ int sig(int j) { return (j ^ (j >> 3)) & 511; }

// twiddles via exact revolution arithmetic: angle -2*pi*t*r/512 -> rev -t*r/512
__device__ __forceinline__ void init_tw(int t, float2* tw0, float2* tw1) {
    tw0[0] = make_float2(1.f, 0.f);
    tw1[0] = make_float2(1.f, 0.f);
    float a0 = -(float)t * (1.0f / 512.0f);
    float a1 = -(float)(t >> 3) * (1.0f / 64.0f);
#pragma unroll
    for (int r = 1; r < 8; ++r) {
        float s, c;
        fsincos_rev(a0 * (float)r, &s, &c); tw0[r] = make_float2(c, s);
        fsincos_rev(a1 * (float)r, &s, &c); tw1[r] = make_float2(c, s);
    }
}

template <int S>
__device__ __forceinline__ void fft512(float2 v[8], float2* lds, int t,
                                       const float2* tw0, const float2* tw1, int rot) {
    float2 b[8];
    dft8<S>(v, b);
#pragma unroll
    for (int r = 1; r < 8; ++r) b[r] = twmul<S>(b[r], tw0[r]);
#pragma unroll
    for (int r = 0; r < 8; ++r) lds[(sig(8 * t + r) + rot) & 511] = b[r];
#pragma unroll
    for (int r = 0; r < 8; ++r) v[r] = lds[(sig(t + 64 * r) + rot) & 511];
    dft8<S>(v, b);
#pragma unroll
    for (int r = 1; r < 8; ++r) b[r] = twmul<S>(b[r], tw1[r]);
    {
        int q = t & 7, p = t >> 3;
#pragma unroll
        for (int r = 0; r < 8; ++r) lds[(sig(q + 64 * p + 8 * r) + rot) & 511] = b[r];
    }
#pragma unroll
    for (int r = 0; r < 8; ++r) v[r] = lds[(sig(t + 64 * r) + rot) & 511];
    dft8<S>(v, b);
#pragma unroll
    for (int r = 0; r < 8; ++r) v[r] = b[r];
}

// ---- init: T tables (3 layers) + H + H^2 -------------------------------------
// Keeps ACCURATE sincosf: H's theta ~ 5.9e5 rad needs exact range reduction.
__global__ __launch_bounds__(256) void k_init(const float* __restrict__ amp,
                                              const float* __restrict__ ph,
                                              float2* __restrict__ Ttab,
                                              float2* __restrict__ Htab,
                                              float2* __restrict__ Htab2) {
    int idx = blockIdx.x * 256 + threadIdx.x;
#pragma unroll
    for (int l = 0; l < 3; ++l) {
        float a = amp[l * HW + idx], p = ph[l * HW + idx];
        float s, c; sincosf(p, &s, &c);
        Ttab[l * HW + idx] = make_float2(a * c, a * s);
    }
    int i = idx >> 9, j = idx & 511;
    const float fscale = 244.140625f;  // 1/(512*8e-6), exact
    float fi = (float)(i < 256 ? i : i - 512) * fscale;
    float fj = (float)(j < 256 ? j : j - 512) * fscale;
    const float lam = 5.32e-07f;
    float ax = lam * fi, ay = lam * fj;
    float arg = 1.0f - ax * ax;
    arg = arg - ay * ay;
    float sq = sqrtf(fmaxf(arg, 0.0f));
    const float kz = (float)(2.0 * 3.14159265358979323846 / 5.32e-07 * 0.05);
    float th = kz * sq;
    float s, c; sincosf(th, &s, &c);
    Htab[idx]  = make_float2(c, s);
    Htab2[idx] = make_float2(c * c - s * s, 2.f * c * s);  // H^2 (fused props 3+4)
}

// ---- K0: E_in * T0, forward row FFT, store fp16 ------------------------------
__global__ __launch_bounds__(256) void k_first(const float* __restrict__ xamp,
                                               const float* __restrict__ noise,
                                               const float2* __restrict__ T0,
                                               __half2* __restrict__ field) {
    __shared__ float2 scr[4][512];
    int t = threadIdx.x & 63, wv = threadIdx.x >> 6;
    int wid = blockIdx.x * 4 + wv;       // [0, 144*512)
    int row = wid & 511, f = wid >> 9;   // f = m*16+b
    int b = f & 15, m = f >> 4;
    float fac = 0.5f * (float)(m + 1);
    float2 tw0[8], tw1[8];
    init_tw(t, tw0, tw1);
    const float*  xr = xamp + (size_t)b * HW + row * 512;
    const float*  nr = noise + (size_t)f * HW + row * 512;
    const float2* Tr = T0 + row * 512;
    float2 v[8];
#pragma unroll
    for (int r = 0; r < 8; ++r) {
        int w = t + 64 * r;
        float pn = nr[w] * fac;
        float s, c; fsincos(pn, &s, &c);
        float xa = xr[w];
        v[r] = cmul(make_float2(xa * c, xa * s), Tr[w]);
    }
    fft512<-1>(v, scr[wv], t, tw0, tw1, 0);
    __half2* out = field + (size_t)f * HW + row * 512;
#pragma unroll
    for (int r = 0; r < 8; ++r) out[t + 64 * r] = __float22half2_rn(v[r]);
}

// ---- K_col: column FFT -> xH -> inverse column FFT (in place, fp16 global) ---
// R6: 8-column / 32 KB tile (was 16/64 KB): LDS allowed only 2 blocks/CU (8
// waves); now 5 blocks fit and the VGPR cap (16 waves/CU) binds. 4 waves x
// 2 serial columns. H prefetched into regs before the forward FFT.
__global__ __launch_bounds__(256) void k_col(__half2* __restrict__ field,
                                             const float2* __restrict__ Htab) {
    __shared__ float2 tile[8 * 512];  // 32 KB fp32, swizzled columns
    int tid = threadIdx.x, t = tid & 63, wv = tid >> 6;
    int fidx = blockIdx.x >> 6;
    int c0   = (blockIdx.x & 63) << 3;
    __half2* fb = field + (size_t)fidx * HW;
    int lcq = tid & 1, hsub = tid >> 1;          // hsub in [0,128)
    int lcb = 4 * lcq;                            // first of 4 columns this lane stages
    float2 tw0[8], tw1[8];
    init_tw(t, tw0, tw1);
#pragma unroll
    for (int it = 0; it < 4; ++it) {
        int h = it * 128 + hsub;
        float4 d = *(const float4*)&fb[(size_t)h * 512 + c0 + lcb];  // 4 complexes
        __half2 hx[4]; *(float4*)hx = d;
#pragma unroll
        for (int k = 0; k < 4; ++k) {
            int lc = lcb + k;
            tile[lc * 512 + ((sig(h) + 2 * lc) & 511)] = __half22float2(hx[k]);
        }
    }
    __syncthreads();
    for (int cc = 0; cc < 2; ++cc) {
        int lc = wv * 2 + cc, col = c0 + lc, rot = 2 * lc;
        float2* lds = tile + lc * 512;
        // H prefetch: loads in flight across the forward FFT
        const float2* Hr = Htab + (size_t)col * 512;  // H symmetric -> coalesced
        float2 hreg[8];
#pragma unroll
        for (int r = 0; r < 8; ++r) hreg[r] = Hr[t + 64 * r];
        float2 v[8];
#pragma unroll
        for (int r = 0; r < 8; ++r) v[r] = lds[(sig(t + 64 * r) + rot) & 511];
        fft512<-1>(v, lds, t, tw0, tw1, rot);
#pragma unroll
        for (int r = 0; r < 8; ++r) v[r] = cmul(v[r], hreg[r]);
        fft512<1>(v, lds, t, tw0, tw1, rot);
        const float inv = 1.0f / 512.0f;
#pragma unroll
        for (int r = 0; r < 8; ++r) {
            v[r].x *= inv; v[r].y *= inv;
            lds[(sig(t + 64 * r) + rot) & 511] = v[r];
        }
    }
    __syncthreads();
#pragma unroll
    for (int it = 0; it < 4; ++it) {
        int h = it * 128 + hsub;
        __half2 hx[4];
#pragma unroll
        for (int k = 0; k < 4; ++k) {
            int lc = lcb + k;
            hx[k] = __float22half2_rn(tile[lc * 512 + ((sig(h) + 2 * lc) & 511)]);
        }
        *(float4*)&fb[(size_t)h * 512 + c0 + lcb] = *(float4*)hx;
    }
}

// ---- K_row: inverse row FFT -> xT -> forward row FFT (in place, fp16) --------
__global__ __launch_bounds__(256) void k_row(__half2* __restrict__ field,
                                             const float2* __restrict__ Tl) {
    __shared__ float2 scr[4][512];
    int t = threadIdx.x & 63, wv = threadIdx.x >> 6;
    int wid = blockIdx.x * 4 + wv;
    int row = wid & 511, f = wid >> 9;
    float2 tw0[8], tw1[8];
    init_tw(t, tw0, tw1);
    __half2* g = field + (size_t)f * HW + row * 512;
    const float2* Tr = Tl + row * 512;
    float2 v[8];
#pragma unroll
    for (int r = 0; r < 8; ++r) v[r] = __half22float2(g[t + 64 * r]);
    fft512<1>(v, scr[wv], t, tw0, tw1, 0);
    const float inv = 1.0f / 512.0f;
#pragma unroll
    for (int r = 0; r < 8; ++r) {
        float2 z = make_float2(v[r].x * inv, v[r].y * inv);
        v[r] = cmul(z, Tr[t + 64 * r]);
    }
    fft512<-1>(v, scr[wv], t, tw0, tw1, 0);
#pragma unroll
    for (int r = 0; r < 8; ++r) g[t + 64 * r] = __float22half2_rn(v[r]);
}

// ---- K_final: inverse row FFT, |.|^2 mean over modes, per-row partials -------
// NO atomics: wave (b,row) writes part[(b*NC+c)*512+row]; k_reduce sums rows.
__global__ __launch_bounds__(256) void k_final(const __half2* __restrict__ field,
                                               const float* __restrict__ mask,
                                               float* __restrict__ part) {
    __shared__ float2 scr[4][512];
    int t = threadIdx.x & 63, wv = threadIdx.x >> 6;
    int wid = blockIdx.x * 4 + wv;  // [0, 16*512)
    int row = wid & 511, b = wid >> 9;
    const __half2* g0 = field + (size_t)b * HW + row * 512;
    float2 nxt[8];
#pragma unroll
    for (int r = 0; r < 8; ++r) nxt[r] = __half22float2(g0[t + 64 * r]);
    float2 tw0[8], tw1[8];
    init_tw(t, tw0, tw1);
    float inten[8];
#pragma unroll
    for (int r = 0; r < 8; ++r) inten[r] = 0.f;
    for (int m = 0; m < NM; ++m) {
        float2 v[8];
#pragma unroll
        for (int r = 0; r < 8; ++r) v[r] = nxt[r];
        if (m < NM - 1) {
            const __half2* gn = field + (size_t)((m + 1) * NB + b) * HW + row * 512;
#pragma unroll
            for (int r = 0; r < 8; ++r) nxt[r] = __half22float2(gn[t + 64 * r]);
        }
        fft512<1>(v, scr[wv], t, tw0, tw1, 0);
#pragma unroll
        for (int r = 0; r < 8; ++r) inten[r] += v[r].x * v[r].x + v[r].y * v[r].y;
    }
    const float sc = 1.0f / (512.0f * 512.0f * 9.0f);  // ifft scale^2 * mean
    const float* mrow = mask + row * 512;
#pragma unroll
    for (int c = 0; c < NC; ++c) {
        float s = 0.f;
#pragma unroll
        for (int r = 0; r < 8; ++r) s += inten[r] * mrow[(size_t)c * HW + t + 64 * r];
        s *= sc;
#pragma unroll
        for (int off = 32; off; off >>= 1) s += __shfl_xor(s, off, 64);
        if (t == 0) part[((size_t)b * NC + c) * 512 + row] = s;
    }
}

// ---- K_reduce: sum 512 row-partials per (b,c); writes every output ------------
__global__ __launch_bounds__(64) void k_reduce(const float* __restrict__ part,
                                               float* __restrict__ out) {
    int bc = blockIdx.x, t = threadIdx.x;
    const float* p = part + (size_t)bc * 512;
    float s = 0.f;
#pragma unroll
    for (int r = 0; r < 8; ++r) s += p[t + 64 * r];
#pragma unroll
    for (int off = 32; off; off >>= 1) s += __shfl_xor(s, off, 64);
    if (t == 0) out[bc] = s;
}

extern "C" void kernel_launch(void* const* d_in, const int* in_sizes, int n_in,
                              void* d_out, int out_size, void* d_ws, size_t ws_size,
                              hipStream_t stream) {
    const float* xamp  = (const float*)d_in[0];
    const float* noise = (const float*)d_in[1];
    const float* amp   = (const float*)d_in[2];
    const float* ph    = (const float*)d_in[3];
    const float* mask  = (const float*)d_in[4];

    char* ws = (char*)d_ws;
    __half2* field = (__half2*)ws;                       // 151 MB (fp16 complex)
    size_t off = (size_t)NF * HW * sizeof(__half2);
    float2* Ttab = (float2*)(ws + off); off += 3ull * HW * sizeof(float2);
    float2* Htab = (float2*)(ws + off); off += (size_t)HW * sizeof(float2);
    float2* Htab2 = (float2*)(ws + off); off += (size_t)HW * sizeof(float2);
    float* part = (float*)(ws + off);                    // 16*10*512 floats

    float* out = (float*)d_out;

    k_init<<<HW / 256, 256, 0, stream>>>(amp, ph, Ttab, Htab, Htab2);
    k_first<<<NF * 512 / 4, 256, 0, stream>>>(xamp, noise, Ttab, field);
    k_col<<<NF * 64, 256, 0, stream>>>(field, Htab);            // prop 1 (h-dim)
    k_row<<<NF * 512 / 4, 256, 0, stream>>>(field, Ttab + HW);  // ifft_w, xT1, fft_w
    k_col<<<NF * 64, 256, 0, stream>>>(field, Htab);            // prop 2
    k_row<<<NF * 512 / 4, 256, 0, stream>>>(field, Ttab + 2 * HW);
    k_col<<<NF * 64, 256, 0, stream>>>(field, Htab2);           // props 3+4 fused (H^2)
    k_final<<<NB * 512 / 4, 256, 0, stream>>>(field, mask, part);
    k_reduce<<<NB * NC, 64, 0, stream>>>(part, out);
}

// Round 7
// 786.930 us; speedup vs baseline: 1.2642x; 1.2642x over previous
//
#include <hip/hip_runtime.h>
#include <hip/hip_fp16.h>
#include <math.h>

// PCDONN: 144 fields (M=9 x B=16) of 512x512 complex through 4 angular-spectrum
// propagations (same z -> same H; last two fused as H^2), 3 masks, intensity
// mean over modes, detector readout.
//
// R3: atomic-free k_final (+k_reduce); fp16 field (151 MB).
// R4: hot-path sincos -> hardware v_sin/v_cos (revolutions); k_init keeps libm.
// R6 FAILED: 8-col tile halved cache-line utilization (FETCH 151->300 MB).
// R7: 16-col tile stored as fp16 (32 KB) + separate fp32 FFT scratch (16 KB):
// full cache lines (FETCH ~151 MB) AND 48 KB LDS -> 3 blocks/CU (12 waves, was 8).
// No extra rounding: tile data is already fp16 in global; FFT math stays fp32.
//
// FFT: per-wave Stockham radix-8 (64 lanes x 8 complex regs, 3 stages),
// XOR-swizzled LDS (sig(j)=j^(j>>3)), no barriers inside (single-wave in-order).

constexpr int HW   = 512 * 512;
constexpr int NF   = 144;  // M*B
constexpr int NB   = 16;
constexpr int NM   = 9;
constexpr int NC   = 10;

__device__ __forceinline__ float2 cmul(float2 a, float2 b) {
    return make_float2(a.x * b.x - a.y * b.y, a.x * b.y + a.y * b.x);
}
__device__ __forceinline__ float2 cadd(float2 a, float2 b) { return make_float2(a.x + b.x, a.y + b.y); }
__device__ __forceinline__ float2 csub(float2 a, float2 b) { return make_float2(a.x - b.x, a.y - b.y); }

template <int S>
__device__ __forceinline__ float2 mulJ(float2 z) {
    return (S < 0) ? make_float2(z.y, -z.x) : make_float2(-z.y, z.x);
}

template <int S>
__device__ __forceinline__ float2 twmul(float2 a, float2 t) {
    float ty = (S < 0) ? t.y : -t.y;
    return make_float2(a.x * t.x - a.y * ty, a.x * ty + a.y * t.x);
}

// fast sincos via v_sin_f32/v_cos_f32 (input in REVOLUTIONS per gfx950 ISA).
__device__ __forceinline__ void fsincos_rev(float rev, float* s, float* c) {
    float r = rev - rintf(rev);       // [-0.5, 0.5]
    *s = __builtin_amdgcn_sinf(r);
    *c = __builtin_amdgcn_cosf(r);
}
// radian-domain version (|x| small, here <= ~25 rad -> reduction err ~1e-6 rad)
__device__ __forceinline__ void fsincos(float x, float* s, float* c) {
    fsincos_rev(x * 0.15915494309189535f, s, c);
}

template <int S>
__device__ __forceinline__ void dft8(const float2 a[8], float2 X[8]) {
    float2 e[4], o[4];
    {
        float2 t0 = cadd(a[0], a[4]), t1 = csub(a[0], a[4]);
        float2 u0 = cadd(a[2], a[6]), u1 = mulJ<S>(csub(a[2], a[6]));
        e[0] = cadd(t0, u0); e[1] = cadd(t1, u1); e[2] = csub(t0, u0); e[3] = csub(t1, u1);
    }
    {
        float2 t0 = cadd(a[1], a[5]), t1 = csub(a[1], a[5]);
        float2 u0 = cadd(a[3], a[7]), u1 = mulJ<S>(csub(a[3], a[7]));
        o[0] = cadd(t0, u0); o[1] = cadd(t1, u1); o[2] = csub(t0, u0); o[3] = csub(t1, u1);
    }
    const float C = 0.70710678118654752f;
    float2 w1 = make_float2(C, (S < 0) ? -C : C);
    float2 w3 = make_float2(-C, (S < 0) ? -C : C);
    o[1] = cmul(o[1], w1);
    o[2] = mulJ<S>(o[2]);
    o[3] = cmul(o[3], w3);
    X[0] = cadd(e[0], o[0]); X[4] = csub(e[0], o[0]);
    X[1] = cadd(e[1], o[1]); X[5] = csub(e[1], o[1]);
    X[2] = cadd(e[2], o[2]); X[6] = csub(e[2], o[2]);
    X[3] = cadd(e[3], o[3]); X[7] = csub(e[3], o[3]);
}

__device__ __forceinline__ int sig(int j) { return (j ^ (j >> 3)) & 511; }

// twiddles via exact revolution arithmetic: angle -2*pi*t*r/512 -> rev -t*r/512
__device__ __forceinline__ void init_tw(int t, float2* tw0, float2* tw1) {
    tw0[0] = make_float2(1.f, 0.f);
    tw1[0] = make_float2(1.f, 0.f);
    float a0 = -(float)t * (1.0f / 512.0f);
    float a1 = -(float)(t >> 3) * (1.0f / 64.0f);
#pragma unroll
    for (int r = 1; r < 8; ++r) {
        float s, c;
        fsincos_rev(a0 * (float)r, &s, &c); tw0[r] = make_float2(c, s);
        fsincos_rev(a1 * (float)r, &s, &c); tw1[r] = make_float2(c, s);
    }
}

template <int S>
__device__ __forceinline__ void fft512(float2 v[8], float2* lds, int t,
                                       const float2* tw0, const float2* tw1, int rot) {
    float2 b[8];
    dft8<S>(v, b);
#pragma unroll
    for (int r = 1; r < 8; ++r) b[r] = twmul<S>(b[r], tw0[r]);
#pragma unroll
    for (int r = 0; r < 8; ++r) lds[(sig(8 * t + r) + rot) & 511] = b[r];
#pragma unroll
    for (int r = 0; r < 8; ++r) v[r] = lds[(sig(t + 64 * r) + rot) & 511];
    dft8<S>(v, b);
#pragma unroll
    for (int r = 1; r < 8; ++r) b[r] = twmul<S>(b[r], tw1[r]);
    {
        int q = t & 7, p = t >> 3;
#pragma unroll
        for (int r = 0; r < 8; ++r) lds[(sig(q + 64 * p + 8 * r) + rot) & 511] = b[r];
    }
#pragma unroll
    for (int r = 0; r < 8; ++r) v[r] = lds[(sig(t + 64 * r) + rot) & 511];
    dft8<S>(v, b);
#pragma unroll
    for (int r = 0; r < 8; ++r) v[r] = b[r];
}

// ---- init: T tables (3 layers) + H + H^2 -------------------------------------
// Keeps ACCURATE sincosf: H's theta ~ 5.9e5 rad needs exact range reduction.
__global__ __launch_bounds__(256) void k_init(const float* __restrict__ amp,
                                              const float* __restrict__ ph,
                                              float2* __restrict__ Ttab,
                                              float2* __restrict__ Htab,
                                              float2* __restrict__ Htab2) {
    int idx = blockIdx.x * 256 + threadIdx.x;
#pragma unroll
    for (int l = 0; l < 3; ++l) {
        float a = amp[l * HW + idx], p = ph[l * HW + idx];
        float s, c; sincosf(p, &s, &c);
        Ttab[l * HW + idx] = make_float2(a * c, a * s);
    }
    int i = idx >> 9, j = idx & 511;
    const float fscale = 244.140625f;  // 1/(512*8e-6), exact
    float fi = (float)(i < 256 ? i : i - 512) * fscale;
    float fj = (float)(j < 256 ? j : j - 512) * fscale;
    const float lam = 5.32e-07f;
    float ax = lam * fi, ay = lam * fj;
    float arg = 1.0f - ax * ax;
    arg = arg - ay * ay;
    float sq = sqrtf(fmaxf(arg, 0.0f));
    const float kz = (float)(2.0 * 3.14159265358979323846 / 5.32e-07 * 0.05);
    float th = kz * sq;
    float s, c; sincosf(th, &s, &c);
    Htab[idx]  = make_float2(c, s);
    Htab2[idx] = make_float2(c * c - s * s, 2.f * c * s);  // H^2 (fused props 3+4)
}

// ---- K0: E_in * T0, forward row FFT, store fp16 ------------------------------
__global__ __launch_bounds__(256) void k_first(const float* __restrict__ xamp,
                                               const float* __restrict__ noise,
                                               const float2* __restrict__ T0,
                                               __half2* __restrict__ field) {
    __shared__ float2 scr[4][512];
    int t = threadIdx.x & 63, wv = threadIdx.x >> 6;
    int wid = blockIdx.x * 4 + wv;       // [0, 144*512)
    int row = wid & 511, f = wid >> 9;   // f = m*16+b
    int b = f & 15, m = f >> 4;
    float fac = 0.5f * (float)(m + 1);
    float2 tw0[8], tw1[8];
    init_tw(t, tw0, tw1);
    const float*  xr = xamp + (size_t)b * HW + row * 512;
    const float*  nr = noise + (size_t)f * HW + row * 512;
    const float2* Tr = T0 + row * 512;
    float2 v[8];
#pragma unroll
    for (int r = 0; r < 8; ++r) {
        int w = t + 64 * r;
        float pn = nr[w] * fac;
        float s, c; fsincos(pn, &s, &c);
        float xa = xr[w];
        v[r] = cmul(make_float2(xa * c, xa * s), Tr[w]);
    }
    fft512<-1>(v, scr[wv], t, tw0, tw1, 0);
    __half2* out = field + (size_t)f * HW + row * 512;
#pragma unroll
    for (int r = 0; r < 8; ++r) out[t + 64 * r] = __float22half2_rn(v[r]);
}

// ---- K_col: column FFT -> xH -> inverse column FFT (in place, fp16 global) ---
// R7: 16-column tile in fp16 (32 KB, full cache lines on staging) + per-wave
// fp32 FFT scratch (16 KB). 48 KB/block -> 3 blocks/CU (12 waves, was 8).
// Staging is raw fp16 moves (no cvt); FFT runs fp32; one fp16 rounding on
// output, same as before. H prefetched into regs before the forward FFT.
__global__ __launch_bounds__(256) void k_col(__half2* __restrict__ field,
                                             const float2* __restrict__ Htab) {
    __shared__ __half2 tile[16 * 512];  // 32 KB, swizzled columns (fp16)
    __shared__ float2  scr[4][512];     // 16 KB, per-wave fp32 FFT scratch
    int tid = threadIdx.x, t = tid & 63, wv = tid >> 6;
    int fidx = blockIdx.x >> 5;
    int c0   = (blockIdx.x & 31) << 4;
    __half2* fb = field + (size_t)fidx * HW;
    int lcq = tid & 3, hsub = tid >> 2;          // hsub in [0,64)
    int lcb = 4 * lcq;                            // first of 4 columns this lane stages
    float2 tw0[8], tw1[8];
    init_tw(t, tw0, tw1);
#pragma unroll
    for (int it = 0; it < 8; ++it) {
        int h = it * 64 + hsub;
        float4 d = *(const float4*)&fb[(size_t)h * 512 + c0 + lcb];  // 4 fp16 complexes
        __half2 hx[4]; *(float4*)hx = d;
#pragma unroll
        for (int k = 0; k < 4; ++k) {
            int lc = lcb + k;
            tile[lc * 512 + ((sig(h) + 2 * lc) & 511)] = hx[k];
        }
    }
    __syncthreads();
    for (int cc = 0; cc < 4; ++cc) {
        int lc = wv * 4 + cc, col = c0 + lc, rot = 2 * lc;
        // H prefetch: loads in flight across the tile read + forward FFT
        const float2* Hr = Htab + (size_t)col * 512;  // H symmetric -> coalesced
        float2 hreg[8];
#pragma unroll
        for (int r = 0; r < 8; ++r) hreg[r] = Hr[t + 64 * r];
        float2 v[8];
#pragma unroll
        for (int r = 0; r < 8; ++r)
            v[r] = __half22float2(tile[lc * 512 + ((sig(t + 64 * r) + rot) & 511)]);
        fft512<-1>(v, scr[wv], t, tw0, tw1, 0);
#pragma unroll
        for (int r = 0; r < 8; ++r) v[r] = cmul(v[r], hreg[r]);
        fft512<1>(v, scr[wv], t, tw0, tw1, 0);
        const float inv = 1.0f / 512.0f;
#pragma unroll
        for (int r = 0; r < 8; ++r) {
            v[r].x *= inv; v[r].y *= inv;
            tile[lc * 512 + ((sig(t + 64 * r) + rot) & 511)] = __float22half2_rn(v[r]);
        }
    }
    __syncthreads();
#pragma unroll
    for (int it = 0; it < 8; ++it) {
        int h = it * 64 + hsub;
        __half2 hx[4];
#pragma unroll
        for (int k = 0; k < 4; ++k) {
            int lc = lcb + k;
            hx[k] = tile[lc * 512 + ((sig(h) + 2 * lc) & 511)];
        }
        *(float4*)&fb[(size_t)h * 512 + c0 + lcb] = *(float4*)hx;
    }
}

// ---- K_row: inverse row FFT -> xT -> forward row FFT (in place, fp16) --------
__global__ __launch_bounds__(256) void k_row(__half2* __restrict__ field,
                                             const float2* __restrict__ Tl) {
    __shared__ float2 scr[4][512];
    int t = threadIdx.x & 63, wv = threadIdx.x >> 6;
    int wid = blockIdx.x * 4 + wv;
    int row = wid & 511, f = wid >> 9;
    float2 tw0[8], tw1[8];
    init_tw(t, tw0, tw1);
    __half2* g = field + (size_t)f * HW + row * 512;
    const float2* Tr = Tl + row * 512;
    float2 v[8];
#pragma unroll
    for (int r = 0; r < 8; ++r) v[r] = __half22float2(g[t + 64 * r]);
    fft512<1>(v, scr[wv], t, tw0, tw1, 0);
    const float inv = 1.0f / 512.0f;
#pragma unroll
    for (int r = 0; r < 8; ++r) {
        float2 z = make_float2(v[r].x * inv, v[r].y * inv);
        v[r] = cmul(z, Tr[t + 64 * r]);
    }
    fft512<-1>(v, scr[wv], t, tw0, tw1, 0);
#pragma unroll
    for (int r = 0; r < 8; ++r) g[t + 64 * r] = __float22half2_rn(v[r]);
}

// ---- K_final: inverse row FFT, |.|^2 mean over modes, per-row partials -------
// NO atomics: wave (b,row) writes part[(b*NC+c)*512+row]; k_reduce sums rows.
__global__ __launch_bounds__(256) void k_final(const __half2* __restrict__ field,
                                               const float* __restrict__ mask,
                                               float* __restrict__ part) {
    __shared__ float2 scr[4][512];
    int t = threadIdx.x & 63, wv = threadIdx.x >> 6;
    int wid = blockIdx.x * 4 + wv;  // [0, 16*512)
    int row = wid & 511, b = wid >> 9;
    const __half2* g0 = field + (size_t)b * HW + row * 512;
    float2 nxt[8];
#pragma unroll
    for (int r = 0; r < 8; ++r) nxt[r] = __half22float2(g0[t + 64 * r]);
    float2 tw0[8], tw1[8];
    init_tw(t, tw0, tw1);
    float inten[8];
#pragma unroll
    for (int r = 0; r < 8; ++r) inten[r] = 0.f;
    for (int m = 0; m < NM; ++m) {
        float2 v[8];
#pragma unroll
        for (int r = 0; r < 8; ++r) v[r] = nxt[r];
        if (m < NM - 1) {
            const __half2* gn = field + (size_t)((m + 1) * NB + b) * HW + row * 512;
#pragma unroll
            for (int r = 0; r < 8; ++r) nxt[r] = __half22float2(gn[t + 64 * r]);
        }
        fft512<1>(v, scr[wv], t, tw0, tw1, 0);
#pragma unroll
        for (int r = 0; r < 8; ++r) inten[r] += v[r].x * v[r].x + v[r].y * v[r].y;
    }
    const float sc = 1.0f / (512.0f * 512.0f * 9.0f);  // ifft scale^2 * mean
    const float* mrow = mask + row * 512;
#pragma unroll
    for (int c = 0; c < NC; ++c) {
        float s = 0.f;
#pragma unroll
        for (int r = 0; r < 8; ++r) s += inten[r] * mrow[(size_t)c * HW + t + 64 * r];
        s *= sc;
#pragma unroll
        for (int off = 32; off; off >>= 1) s += __shfl_xor(s, off, 64);
        if (t == 0) part[((size_t)b * NC + c) * 512 + row] = s;
    }
}

// ---- K_reduce: sum 512 row-partials per (b,c); writes every output ------------
__global__ __launch_bounds__(64) void k_reduce(const float* __restrict__ part,
                                               float* __restrict__ out) {
    int bc = blockIdx.x, t = threadIdx.x;
    const float* p = part + (size_t)bc * 512;
    float s = 0.f;
#pragma unroll
    for (int r = 0; r < 8; ++r) s += p[t + 64 * r];
#pragma unroll
    for (int off = 32; off; off >>= 1) s += __shfl_xor(s, off, 64);
    if (t == 0) out[bc] = s;
}

extern "C" void kernel_launch(void* const* d_in, const int* in_sizes, int n_in,
                              void* d_out, int out_size, void* d_ws, size_t ws_size,
                              hipStream_t stream) {
    const float* xamp  = (const float*)d_in[0];
    const float* noise = (const float*)d_in[1];
    const float* amp   = (const float*)d_in[2];
    const float* ph    = (const float*)d_in[3];
    const float* mask  = (const float*)d_in[4];

    char* ws = (char*)d_ws;
    __half2* field = (__half2*)ws;                       // 151 MB (fp16 complex)
    size_t off = (size_t)NF * HW * sizeof(__half2);
    float2* Ttab = (float2*)(ws + off); off += 3ull * HW * sizeof(float2);
    float2* Htab = (float2*)(ws + off); off += (size_t)HW * sizeof(float2);
    float2* Htab2 = (float2*)(ws + off); off += (size_t)HW * sizeof(float2);
    float* part = (float*)(ws + off);                    // 16*10*512 floats

    float* out = (float*)d_out;

    k_init<<<HW / 256, 256, 0, stream>>>(amp, ph, Ttab, Htab, Htab2);
    k_first<<<NF * 512 / 4, 256, 0, stream>>>(xamp, noise, Ttab, field);
    k_col<<<NF * 32, 256, 0, stream>>>(field, Htab);            // prop 1 (h-dim)
    k_row<<<NF * 512 / 4, 256, 0, stream>>>(field, Ttab + HW);  // ifft_w, xT1, fft_w
    k_col<<<NF * 32, 256, 0, stream>>>(field, Htab);            // prop 2
    k_row<<<NF * 512 / 4, 256, 0, stream>>>(field, Ttab + 2 * HW);
    k_col<<<NF * 32, 256, 0, stream>>>(field, Htab2);           // props 3+4 fused (H^2)
    k_final<<<NB * 512 / 4, 256, 0, stream>>>(field, mask, part);
    k_reduce<<<NB * NC, 64, 0, stream>>>(part, out);
}